// Round 3
// baseline (413.281 us; speedup 1.0000x reference)
//
#include <hip/hip_runtime.h>
#include <hip/hip_bf16.h>
#include <stdint.h>

// Problem constants
#define S_LEN 1024
#define B_SZ  64
#define I_SZ  512
#define H_SZ  2048
#define O_SZ  512

typedef __bf16  bf16x8 __attribute__((ext_vector_type(8)));
typedef float   f32x4  __attribute__((ext_vector_type(4)));

static __device__ __forceinline__ ushort f2bf(float f) {
  union { float f; unsigned u; } v; v.f = f;
  unsigned r = v.u + 0x7FFFu + ((v.u >> 16) & 1u);   // RNE
  return (ushort)(r >> 16);
}
static __device__ __forceinline__ float bf2f(ushort u) {
  return __builtin_bit_cast(float, (unsigned)u << 16);
}

// async global->LDS, 16B per lane, wave-uniform LDS base + lane*16
#define GLOAD_LDS16(gp, lp) \
  __builtin_amdgcn_global_load_lds( \
      (__attribute__((address_space(1))) void*)(gp), \
      (__attribute__((address_space(3))) void*)(lp), 16, 0, 0)

// ---------------------------------------------------------------- W convert (tiny)
__global__ __launch_bounds__(256) void convert_f32_bf16_kernel(
    const float4* __restrict__ in, ushort4* __restrict__ out, int n4) {
  int i = blockIdx.x * 256 + threadIdx.x;
  if (i >= n4) return;
  float4 v = in[i];
  ushort4 o; o.x = f2bf(v.x); o.y = f2bf(v.y); o.z = f2bf(v.z); o.w = f2bf(v.w);
  out[i] = o;
}

// ---------------------------------------------------------------- X convert+transpose
// X[s][b][i] fp32 -> Xbf[b][s][i] bf16. One wave per (s,b) row: 64 lanes x
// 8 floats = 512. Reads 2KB contiguous/wave, writes 1KB contiguous/wave.
__global__ __launch_bounds__(256) void convert_x_kernel(
    const float* __restrict__ X, ushort* __restrict__ Xt) {
  const int row  = blockIdx.x * 4 + (threadIdx.x >> 6);  // s*64 + b
  const int lane = threadIdx.x & 63;
  const int s = row >> 6, b = row & 63;
  const float* src = X + (size_t)row * I_SZ + lane * 8;
  float4 v0 = *(const float4*)src;
  float4 v1 = *(const float4*)(src + 4);
  union { ushort h[8]; uint4 v; } o;
  o.h[0] = f2bf(v0.x); o.h[1] = f2bf(v0.y); o.h[2] = f2bf(v0.z); o.h[3] = f2bf(v0.w);
  o.h[4] = f2bf(v1.x); o.h[5] = f2bf(v1.y); o.h[6] = f2bf(v1.z); o.h[7] = f2bf(v1.w);
  *(uint4*)(Xt + ((size_t)b * S_LEN + s) * I_SZ + lane * 8) = o.v;
}

// ---------------------------------------------------------------- Y = bias (runs BEFORE fused)
__global__ __launch_bounds__(256) void init_y_kernel(
    const float* __restrict__ bho, float* __restrict__ Y) {
  int idx = blockIdx.x * 256 + threadIdx.x;   // 0..32767
  Y[idx] = bho[idx & (O_SZ - 1)];
}

#define SCAN16(colp, s0_) do { \
    ushort4 v0 = *(const ushort4*)&(colp)[(s0_)]; \
    ushort4 v1 = *(const ushort4*)&(colp)[(s0_) + 4]; \
    ushort4 v2 = *(const ushort4*)&(colp)[(s0_) + 8]; \
    ushort4 v3 = *(const ushort4*)&(colp)[(s0_) + 12]; \
    p = fmaf(c, fabsf(p), bf2f(v0.x)); p = fmaf(c, fabsf(p), bf2f(v0.y)); \
    p = fmaf(c, fabsf(p), bf2f(v0.z)); p = fmaf(c, fabsf(p), bf2f(v0.w)); \
    p = fmaf(c, fabsf(p), bf2f(v1.x)); p = fmaf(c, fabsf(p), bf2f(v1.y)); \
    p = fmaf(c, fabsf(p), bf2f(v1.z)); p = fmaf(c, fabsf(p), bf2f(v1.w)); \
    p = fmaf(c, fabsf(p), bf2f(v2.x)); p = fmaf(c, fabsf(p), bf2f(v2.y)); \
    p = fmaf(c, fabsf(p), bf2f(v2.z)); p = fmaf(c, fabsf(p), bf2f(v2.w)); \
    p = fmaf(c, fabsf(p), bf2f(v3.x)); p = fmaf(c, fabsf(p), bf2f(v3.y)); \
    p = fmaf(c, fabsf(p), bf2f(v3.z)); p = fmaf(c, fabsf(p), bf2f(v3.w)); \
  } while (0)

// ---------------------------------------------------------------- fused GEMM + scan + projection
// Grid: 1024 blocks = (b, ht). R0-proven skeleton (2 plain syncs/kt, serial
// scan at s-tile end, Cs overlays As+Bs), but BOTH operands now staged with
// global_load_lds from bf16 (A from pre-converted batch-major Xbf), using the
// proven B rotate-swizzle pattern for both. No in-loop cvt, no reg prefetch.
// LDS 33792 B -> up to 4 blocks/CU. Tail: h projected through Who into Y.
__global__ __launch_bounds__(256, 3) void fused_gemm_scan_kernel(
    const ushort* __restrict__ Xbf,   // [64][1024][512] bf16, batch-major
    const ushort* __restrict__ Wbf,   // [2048][512] bf16
    const float* __restrict__ hh,     // [2048]
    const float* __restrict__ Who,    // [512][2048] fp32
    float* __restrict__ Y) {          // [64][512], pre-seeded with bias
  __shared__ __align__(16) ushort smem[16896];   // 33792 B
  ushort* As = smem;                  // [128][64], rotate-swizzled
  ushort* Bs = smem + 8192;           // [128][64], rotate-swizzled
  ushort* Cs = smem;                  // [128 h][132 s] overlay (16896 us)

  const int tid  = threadIdx.x;
  const int wave = tid >> 6;
  const int lane = tid & 63;

  const int bid = blockIdx.x;
  const int xcd = bid & 7;            // XCD (bid%8 heuristic)
  const int g   = bid >> 3;           // 0..127
  const int b   = (xcd << 3) | (g & 7);  // same-b -> same XCD (Xbf L2 reuse)
  const int ht  = g >> 3;             // h-tile 0..15

  const int wm = (wave >> 1) * 64;    // s-offset within tile
  const int wn = (wave & 1) * 64;     // h-offset within tile
  const int ml = lane & 15;
  const int q  = lane >> 4;

  // ---- staging pattern (identical for A and B): wave stages 32 rows of 64
  //      bf16; slot s of LDS row holds global chunk (s - row)&7 (rotate).
  const int r0     = wave * 32;
  const int srow   = lane >> 3;
  const int schunk = ((lane & 7) - srow) & 7;
  const ushort* gA = Xbf + (size_t)b * (S_LEN * I_SZ)
                   + (size_t)(r0 + srow) * I_SZ + schunk * 8;
  const ushort* gB = Wbf + (size_t)(ht * 128 + r0 + srow) * I_SZ + schunk * 8;
  ushort* lA = As + r0 * 64;
  ushort* lB = Bs + r0 * 64;

  // fragment offsets: chunk ks*4+q of row r lives at slot (ks*4+q + r)&7
  int foff[2];
  foff[0] = ((q + ml) & 7) * 8;
  foff[1] = ((4 + q + ml) & 7) * 8;
  int arow[4], brow[4];
  #pragma unroll
  for (int i = 0; i < 4; ++i) {
    arow[i] = (wm + i * 16 + ml) * 64;
    brow[i] = (wn + i * 16 + ml) * 64;
  }

  float c = 0.0f, p = 0.0f;           // scan state (p: pre-abs h)
  if (tid < 128) c = hh[ht * 128 + tid];

  #pragma unroll 1
  for (int st = 0; st < 8; ++st) {
    f32x4 acc[4][4] = {};

    for (int kt = 0; kt < 8; ++kt) {
      __syncthreads();   // prev frag reads / scan done before restaging
      const ushort* ga = gA + (size_t)st * (128 * I_SZ) + kt * 64;
      const ushort* gb = gB + kt * 64;
      #pragma unroll
      for (int jj = 0; jj < 4; ++jj) {
        GLOAD_LDS16(ga + (size_t)(jj * 8) * I_SZ, lA + jj * 512);
        GLOAD_LDS16(gb + (size_t)(jj * 8) * I_SZ, lB + jj * 512);
      }
      __syncthreads();   // staging visible
      #pragma unroll
      for (int ks = 0; ks < 2; ++ks) {
        bf16x8 af[4], bfr[4];
        #pragma unroll
        for (int i = 0; i < 4; ++i) {
          af[i]  = *(const bf16x8*)&As[arow[i] + foff[ks]];
          bfr[i] = *(const bf16x8*)&Bs[brow[i] + foff[ks]];
        }
        __builtin_amdgcn_s_setprio(1);
        #pragma unroll
        for (int mi = 0; mi < 4; ++mi)
          #pragma unroll
          for (int ni = 0; ni < 4; ++ni)
            acc[mi][ni] = __builtin_amdgcn_mfma_f32_16x16x32_bf16(
                af[mi], bfr[ni], acc[mi][ni], 0, 0, 0);
        __builtin_amdgcn_s_setprio(0);
      }
    }

    // epilogue: acc -> transposed Cs[h][s] (overlay; frag reads done at sync)
    __syncthreads();
    const int sb = wm + q * 4;
    #pragma unroll
    for (int mi = 0; mi < 4; ++mi) {
      #pragma unroll
      for (int ni = 0; ni < 4; ++ni) {
        ushort4 o;
        o.x = f2bf(acc[mi][ni][0]); o.y = f2bf(acc[mi][ni][1]);
        o.z = f2bf(acc[mi][ni][2]); o.w = f2bf(acc[mi][ni][3]);
        *(ushort4*)&Cs[(wn + ni * 16 + ml) * 132 + sb + mi * 16] = o;
      }
    }
    __syncthreads();

    // scan: 128 threads, one h-column each (next kt0-sync orders vs restage)
    if (tid < 128) {
      const ushort* col = &Cs[tid * 132];
      #pragma unroll
      for (int s0 = 0; s0 < 128; s0 += 16) {
        SCAN16(col, s0);
      }
    }
  }

  __syncthreads();                     // all scans done; Cs/As free
  if (tid < 128) ((float*)smem)[tid] = fabsf(p);   // h handoff
  __syncthreads();

  // ---- Y[b, :] += h . Who[:, ht*128 .. +128)   (Who slice is L2-resident)
  {
    const float* hs = (const float*)smem;
    const float* w0 = Who + (size_t)tid * H_SZ + (size_t)ht * 128;
    const float* w1 = w0 + (size_t)256 * H_SZ;
    float y0 = 0.f, y1 = 0.f;
    #pragma unroll 8
    for (int k = 0; k < 128; k += 4) {
      float4 hv = *(const float4*)&hs[k];    // broadcast (same addr all lanes)
      float4 u0 = *(const float4*)&w0[k];
      float4 u1 = *(const float4*)&w1[k];
      y0 += hv.x * u0.x + hv.y * u0.y + hv.z * u0.z + hv.w * u0.w;
      y1 += hv.x * u1.x + hv.y * u1.y + hv.z * u1.z + hv.w * u1.w;
    }
    atomicAdd(&Y[(size_t)b * O_SZ + tid], y0);
    atomicAdd(&Y[(size_t)b * O_SZ + 256 + tid], y1);
  }
}

// ---------------------------------------------------------------- launch
extern "C" void kernel_launch(void* const* d_in, const int* in_sizes, int n_in,
                              void* d_out, int out_size, void* d_ws, size_t ws_size,
                              hipStream_t stream) {
  (void)in_sizes; (void)n_in; (void)out_size; (void)ws_size;
  const float* X   = (const float*)d_in[0];   // [1024][64][512]
  const float* Wih = (const float*)d_in[1];   // [2048][512]
  const float* hh  = (const float*)d_in[2];   // [2048]
  const float* Who = (const float*)d_in[3];   // [512][2048]
  const float* bho = (const float*)d_in[4];   // [512]
  float* Y = (float*)d_out;                   // [64][512]

  const size_t WBF = (size_t)H_SZ * I_SZ * 2;          // 2 MiB
  char* w = (char*)d_ws;
  ushort* Wbf = (ushort*)w;                            // 2 MiB
  ushort* Xbf = (ushort*)(w + WBF);                    // 64 MiB, [b][s][i]

  // W convert (tiny)
  {
    int n4w = (int)((size_t)H_SZ * I_SZ / 4);          // 262144
    convert_f32_bf16_kernel<<<n4w / 256, 256, 0, stream>>>(
        (const float4*)Wih, (ushort4*)Wbf, n4w);
  }

  // X convert + transpose to batch-major bf16
  convert_x_kernel<<<(S_LEN * B_SZ) / 4, 256, 0, stream>>>(X, Xbf);

  // Y <- bias (must complete before fused kernel's atomics; stream-ordered)
  init_y_kernel<<<(B_SZ * O_SZ) / 256, 256, 0, stream>>>(bho, Y);

  // fused GEMM + scan + projection
  fused_gemm_scan_kernel<<<1024, 256, 0, stream>>>(Xbf, Wbf, hh, Who, Y);
}